// Round 5
// baseline (536.109 us; speedup 1.0000x reference)
//
#include <hip/hip_runtime.h>
#include <hip/hip_cooperative_groups.h>
#include <math.h>

#define N_NODES 50000
#define N_EDGES 800000
#define HIDDEN  256
#define OUT_DIM 10
#define LN_EPS  1e-5f

#define NP    8                    // node partitions
#define PART  (N_NODES / NP)       // 6250 nodes per partition
#define ES    32                   // edge slices
#define EPSE  (N_EDGES / ES)       // 25000 edges per slice
#define NBLK  (NP * ES)            // 256 blocks == 256 CUs (co-resident)
#define NTHR  1024
#define NWAVE (NBLK * NTHR / 64)   // 4096 waves
#define NBAR  5

// Lightweight grid barrier: one leader lane per block arrives (release) and
// spins; everyone else parks at the block barrier. 256 spinners instead of
// 262144 (cg::grid.sync's all-thread spin measured ~35us/sync on MI355X).
__device__ __forceinline__ void gbar(unsigned* cnt) {
    __syncthreads();
    if (threadIdx.x == 0) {
        __threadfence();   // release: block's writes visible device-wide
        __hip_atomic_fetch_add(cnt, 1u, __ATOMIC_RELEASE, __HIP_MEMORY_SCOPE_AGENT);
        while (__hip_atomic_load(cnt, __ATOMIC_ACQUIRE, __HIP_MEMORY_SCOPE_AGENT) < (unsigned)NBLK)
            __builtin_amdgcn_s_sleep(2);
    }
    __syncthreads();
    __threadfence();       // acquire for all threads of the block
}

__global__ __launch_bounds__(NTHR) void mega_kernel(
    const int* __restrict__ src, const int* __restrict__ dst,
    const float2* __restrict__ nf,
    const float* __restrict__ Wg, const float* __restrict__ bg,
    const float* __restrict__ gamma, const float* __restrict__ beta,
    const float* __restrict__ Wh, const float* __restrict__ bh,
    const float* __restrict__ Wo, const float* __restrict__ bo,
    unsigned* __restrict__ bar,    // [NBAR] barrier counters (zeroed per call)
    unsigned* __restrict__ degp,   // [ES][N] degree partials
    float* __restrict__ Tpart,     // [ES][2N] scatter partials
    float* __restrict__ dinv,      // [N]
    float2* __restrict__ y,        // [N]  y = dinv * x
    float* __restrict__ T,         // [2N] reduced scatter
    float* __restrict__ Ppart,     // [NBLK][HIDDEN] pooled partials
    float* __restrict__ out)
{
    __shared__ float smem[2 * PART];           // 50 KB, reused per phase

    const int tid   = threadIdx.x;
    const int bid   = blockIdx.x;
    const int slice = bid & (ES - 1);
    const int part  = bid >> 5;                // bid / ES
    const int base  = part * PART;
    const int e0    = slice * EPSE;

    // ---------------- phase 1: privatized degree histogram ----------------
    {
        unsigned* hist = (unsigned*)smem;
        for (int i = tid; i < PART; i += NTHR) hist[i] = 0u;
        __syncthreads();
        for (int e = e0 + tid; e < e0 + EPSE; e += NTHR) {
            const unsigned r = (unsigned)(dst[e] - base);
            if (r < PART) atomicAdd(&hist[r], 1u);
        }
        __syncthreads();
        unsigned* outp = degp + (size_t)slice * N_NODES + base;
        for (int i = tid; i < PART; i += NTHR) outp[i] = hist[i];
    }
    gbar(&bar[0 * 16]);

    // ---------------- phase 2: deg -> dinv, y = dinv * x ------------------
    {
        const int gt = bid * NTHR + tid;
        if (gt < N_NODES) {
            unsigned d = 0;
            #pragma unroll
            for (int s = 0; s < ES; ++s) d += degp[(size_t)s * N_NODES + gt];
            const float di = rsqrtf((float)d + 1.0f);
            dinv[gt] = di;
            const float2 x = nf[gt];
            y[gt] = make_float2(di * x.x, di * x.y);
        }
    }
    gbar(&bar[1 * 16]);

    // ---------------- phase 3: privatized edge scatter --------------------
    {
        float* Tl = smem;
        for (int i = tid; i < 2 * PART; i += NTHR) Tl[i] = 0.f;
        __syncthreads();
        for (int e = e0 + tid; e < e0 + EPSE; e += NTHR) {
            const unsigned r = (unsigned)(dst[e] - base);
            if (r < PART) {
                const float2 ys = y[src[e]];
                atomicAdd(&Tl[2 * r],     ys.x);
                atomicAdd(&Tl[2 * r + 1], ys.y);
            }
        }
        __syncthreads();
        float* outp = Tpart + (size_t)slice * (2 * N_NODES) + 2 * base;
        for (int i = tid; i < 2 * PART; i += NTHR) outp[i] = Tl[i];
    }
    gbar(&bar[2 * 16]);

    // ---------------- phase 4a: coalesced Tpart -> T reduce ---------------
    {
        const int gt = bid * NTHR + tid;
        for (int i = gt; i < 2 * N_NODES; i += NBLK * NTHR) {
            float s = 0.f;
            #pragma unroll
            for (int p = 0; p < ES; ++p) s += Tpart[(size_t)p * (2 * N_NODES) + i];
            T[i] = s;
        }
    }
    gbar(&bar[3 * 16]);

    // -------- phase 4b: GCN expand + ReLU + LayerNorm + pool partials -----
    {
        const int lane = tid & 63;
        const int wv   = tid >> 6;
        const int gw   = (bid * NTHR + tid) >> 6;

        const float4 w0  = *reinterpret_cast<const float4*>(&Wg[lane * 4]);
        const float4 w1  = *reinterpret_cast<const float4*>(&Wg[HIDDEN + lane * 4]);
        const float4 bgv = *reinterpret_cast<const float4*>(&bg[lane * 4]);
        const float4 gv  = *reinterpret_cast<const float4*>(&gamma[lane * 4]);
        const float4 bv  = *reinterpret_cast<const float4*>(&beta[lane * 4]);

        float a0 = 0.f, a1 = 0.f, a2 = 0.f, a3 = 0.f;

        for (int n = gw; n < N_NODES; n += NWAVE) {
            const float di = dinv[n];
            const float2 tn = *reinterpret_cast<const float2*>(&T[2 * n]);
            const float2 yn = y[n];
            const float s0 = di * (tn.x + yn.x);
            const float s1 = di * (tn.y + yn.y);

            float v0 = fmaxf(fmaf(s1, w1.x, fmaf(s0, w0.x, bgv.x)), 0.f);
            float v1 = fmaxf(fmaf(s1, w1.y, fmaf(s0, w0.y, bgv.y)), 0.f);
            float v2 = fmaxf(fmaf(s1, w1.z, fmaf(s0, w0.z, bgv.z)), 0.f);
            float v3 = fmaxf(fmaf(s1, w1.w, fmaf(s0, w0.w, bgv.w)), 0.f);

            float sum = v0 + v1 + v2 + v3;
            float sq  = v0 * v0 + v1 * v1 + v2 * v2 + v3 * v3;
            #pragma unroll
            for (int o = 1; o < 64; o <<= 1) {
                sum += __shfl_xor(sum, o, 64);
                sq  += __shfl_xor(sq,  o, 64);
            }
            const float mu   = sum * (1.0f / HIDDEN);
            const float var  = sq * (1.0f / HIDDEN) - mu * mu;
            const float rstd = rsqrtf(var + LN_EPS);

            a0 += (v0 - mu) * rstd * gv.x + bv.x;
            a1 += (v1 - mu) * rstd * gv.y + bv.y;
            a2 += (v2 - mu) * rstd * gv.z + bv.z;
            a3 += (v3 - mu) * rstd * gv.w + bv.w;
        }

        float* red = smem;                     // [16][HIDDEN]
        red[wv * HIDDEN + lane * 4 + 0] = a0;
        red[wv * HIDDEN + lane * 4 + 1] = a1;
        red[wv * HIDDEN + lane * 4 + 2] = a2;
        red[wv * HIDDEN + lane * 4 + 3] = a3;
        __syncthreads();
        if (tid < HIDDEN) {
            float s = 0.f;
            #pragma unroll
            for (int w = 0; w < 16; ++w) s += red[w * HIDDEN + tid];
            Ppart[(size_t)bid * HIDDEN + tid] = s;
        }
    }
    gbar(&bar[4 * 16]);

    // ---------------- phase 5: pooled reduce + MLP head (block 0) ---------
    if (bid == 0) {
        float* red4 = smem;                    // [4][HIDDEN]
        float* p    = smem + 4 * HIDDEN;       // [HIDDEN]
        float* z    = p + HIDDEN;              // [HIDDEN]
        float* lg   = z + HIDDEN;              // [OUT_DIM]

        const int j = tid & (HIDDEN - 1);
        const int g = tid >> 8;                // 0..3
        float s = 0.f;
        for (int b = g * 64; b < g * 64 + 64; ++b)
            s += Ppart[(size_t)b * HIDDEN + j];
        red4[g * HIDDEN + j] = s;
        __syncthreads();

        if (tid < HIDDEN)
            p[tid] = red4[tid] + red4[HIDDEN + tid] + red4[2 * HIDDEN + tid] + red4[3 * HIDDEN + tid];
        __syncthreads();

        if (tid < HIDDEN) {
            float s2 = bh[tid];
            for (int k = 0; k < HIDDEN; ++k) s2 = fmaf(p[k], Wh[k * HIDDEN + tid], s2);
            z[tid] = fmaxf(s2, 0.f);
        }
        __syncthreads();

        if (tid < OUT_DIM) {
            float t = bo[tid];
            for (int k = 0; k < HIDDEN; ++k) t = fmaf(z[k], Wo[k * OUT_DIM + tid], t);
            lg[tid] = t;
        }
        __syncthreads();

        if (tid == 0) {
            float m = lg[0];
            for (int k = 1; k < OUT_DIM; ++k) m = fmaxf(m, lg[k]);
            float sum = 0.f;
            for (int k = 0; k < OUT_DIM; ++k) sum += expf(lg[k] - m);
            const float lse = m + logf(sum);
            for (int k = 0; k < OUT_DIM; ++k) out[k] = lg[k] - lse;
        }
    }
}

// ---------------------------------------------------------------- launch ----
extern "C" void kernel_launch(void* const* d_in, const int* in_sizes, int n_in,
                              void* d_out, int out_size, void* d_ws, size_t ws_size,
                              hipStream_t stream) {
    const float2* nf   = (const float2*)d_in[0];  // [N, 2]
    const int*   ei    = (const int*)  d_in[1];   // [2, E] int32
    const float* Wg    = (const float*)d_in[2];
    const float* bg    = (const float*)d_in[3];
    const float* gamma = (const float*)d_in[4];
    const float* beta  = (const float*)d_in[5];
    const float* Wh    = (const float*)d_in[6];
    const float* bh    = (const float*)d_in[7];
    const float* Wo    = (const float*)d_in[8];
    const float* bo    = (const float*)d_in[9];
    float* out = (float*)d_out;

    const int* srcp = ei;
    const int* dstp = ei + N_EDGES;

    // workspace: bar [5*16 u32, 64B-spaced] | degp [ES*N] u32 | Tpart [ES*2N]
    //            | dinv [N] | y [2N] | T [2N] | Ppart [NBLK*H]   (~20.5 MB)
    unsigned* bar  = (unsigned*)d_ws;
    unsigned* degp = bar + NBAR * 16;
    float* Tpart   = (float*)(degp + (size_t)ES * N_NODES);
    float* dinvp   = Tpart + (size_t)ES * 2 * N_NODES;
    float* yp      = dinvp + N_NODES;
    float* Tp      = yp + 2 * N_NODES;
    float* Ppart   = Tp + 2 * N_NODES;

    hipMemsetAsync(bar, 0, NBAR * 16 * sizeof(unsigned), stream);

    void* args[] = {
        (void*)&srcp, (void*)&dstp, (void*)&nf,
        (void*)&Wg, (void*)&bg, (void*)&gamma, (void*)&beta,
        (void*)&Wh, (void*)&bh, (void*)&Wo, (void*)&bo,
        (void*)&bar, (void*)&degp, (void*)&Tpart, (void*)&dinvp, (void*)&yp,
        (void*)&Tp, (void*)&Ppart, (void*)&out
    };
    hipLaunchCooperativeKernel((const void*)mega_kernel, dim3(NBLK), dim3(NTHR),
                               args, 0, stream);
}

// Round 6
// 68.539 us; speedup vs baseline: 7.8220x; 7.8220x over previous
//
#include <hip/hip_runtime.h>
#include <math.h>

#define N_NODES 50000
#define N_EDGES 800000
#define HIDDEN  256
#define OUT_DIM 10
#define LN_EPS  1e-5f

#define NP    8                    // node partitions
#define PART  (N_NODES / NP)       // 6250 nodes per partition
#define ES    32                   // edge slices
#define EPSE  (N_EDGES / ES)       // 25000 edges per slice
#define NPB   196                  // nodes per ln_pool block (196*256 >= 50000)

// --------------------------------------------------- privatized histogram ----
// Block (slice, part): LDS histogram of its node range over its edge slice.
// Partials stored as u16 (max 25000 per slice fits).
__global__ __launch_bounds__(1024) void hist_kernel(const int* __restrict__ dst,
                                                    unsigned short* __restrict__ degp) {
    __shared__ unsigned hist[PART];          // 25 KB
    const int tid = threadIdx.x;
    for (int i = tid; i < PART; i += 1024) hist[i] = 0u;
    __syncthreads();

    const int base = blockIdx.y * PART;
    const int e0 = blockIdx.x * EPSE, e1 = e0 + EPSE;
    for (int e = e0 + tid; e < e1; e += 1024) {
        const unsigned r = (unsigned)(dst[e] - base);
        if (r < PART) atomicAdd(&hist[r], 1u);
    }
    __syncthreads();

    unsigned short* outp = degp + (size_t)blockIdx.x * N_NODES + base;
    for (int i = tid; i < PART; i += 1024) outp[i] = (unsigned short)hist[i];
}

// deg partials -> dinv[n] = rsqrt(deg+1), y[n] = dinv[n] * x[n]
__global__ __launch_bounds__(256) void dinv_y_kernel(const unsigned short* __restrict__ degp,
                                                     const float2* __restrict__ nf,
                                                     float* __restrict__ dinv,
                                                     float2* __restrict__ y) {
    const int t = blockIdx.x * 256 + threadIdx.x;
    if (t >= N_NODES) return;
    unsigned deg = 0;
    #pragma unroll
    for (int s = 0; s < ES; ++s) deg += degp[(size_t)s * N_NODES + t];
    const float di = rsqrtf((float)deg + 1.0f);
    dinv[t] = di;
    const float2 x = nf[t];
    y[t] = make_float2(di * x.x, di * x.y);
}

// ------------------------------------------------ privatized edge scatter ----
// Tpart[slice][d] = sum over slice's edges with dst=d of y[src]
__global__ __launch_bounds__(1024) void scatterp_kernel(const int* __restrict__ src,
                                                        const int* __restrict__ dst,
                                                        const float2* __restrict__ y,
                                                        float* __restrict__ Tpart) {
    __shared__ float T[2 * PART];            // 50 KB
    const int tid = threadIdx.x;
    for (int i = tid; i < 2 * PART; i += 1024) T[i] = 0.f;
    __syncthreads();

    const int base = blockIdx.y * PART;
    const int e0 = blockIdx.x * EPSE, e1 = e0 + EPSE;
    for (int e = e0 + tid; e < e1; e += 1024) {
        const unsigned r = (unsigned)(dst[e] - base);
        if (r < PART) {
            const float2 ys = y[src[e]];
            atomicAdd(&T[2 * r],     ys.x);
            atomicAdd(&T[2 * r + 1], ys.y);
        }
    }
    __syncthreads();

    float* outp = Tpart + (size_t)blockIdx.x * (2 * N_NODES) + 2 * base;
    for (int i = tid; i < 2 * PART; i += 1024) outp[i] = T[i];
}

// ------------- Tpart reduce (block-local) + GCN expand + ReLU + LN + pool ----
// Block b owns nodes [b*NPB, b*NPB+NPB): reduces its slice of Tpart into LDS
// (no grid-wide boundary needed), then wave-per-node LN, then plain-stores
// one pooled partial row. Zero global atomics, zero memsets.
__global__ __launch_bounds__(1024) void ln_pool_kernel(const float* __restrict__ Tpart,
                                                       const float2* __restrict__ y,
                                                       const float* __restrict__ dinv,
                                                       const float* __restrict__ Wg,
                                                       const float* __restrict__ bg,
                                                       const float* __restrict__ gamma,
                                                       const float* __restrict__ beta,
                                                       float* __restrict__ Ppart) {
    const int tid = threadIdx.x;
    const int bid = blockIdx.x;
    const int n0  = bid * NPB;
    const int n1  = (n0 + NPB < N_NODES) ? n0 + NPB : N_NODES;
    const int len2 = 2 * (n1 - n0);

    __shared__ float Tloc[2 * NPB];          // 1.57 KB
    __shared__ float red[16][HIDDEN];        // 16 KB

    // block-local Tpart reduction (coalesced runs of len2 floats per slice)
    for (int i = tid; i < len2; i += 1024) {
        float s = 0.f;
        #pragma unroll
        for (int p = 0; p < ES; ++p) s += Tpart[(size_t)p * (2 * N_NODES) + 2 * n0 + i];
        Tloc[i] = s;
    }
    __syncthreads();

    const int lane = tid & 63;
    const int wv   = tid >> 6;

    const float4 w0  = *reinterpret_cast<const float4*>(&Wg[lane * 4]);
    const float4 w1  = *reinterpret_cast<const float4*>(&Wg[HIDDEN + lane * 4]);
    const float4 bgv = *reinterpret_cast<const float4*>(&bg[lane * 4]);
    const float4 gv  = *reinterpret_cast<const float4*>(&gamma[lane * 4]);
    const float4 bv  = *reinterpret_cast<const float4*>(&beta[lane * 4]);

    float a0 = 0.f, a1 = 0.f, a2 = 0.f, a3 = 0.f;

    for (int n = n0 + wv; n < n1; n += 16) {
        const float di = dinv[n];
        const float2 yn = y[n];
        const float s0 = di * (Tloc[2 * (n - n0)]     + yn.x);
        const float s1 = di * (Tloc[2 * (n - n0) + 1] + yn.y);

        float v0 = fmaxf(fmaf(s1, w1.x, fmaf(s0, w0.x, bgv.x)), 0.f);
        float v1 = fmaxf(fmaf(s1, w1.y, fmaf(s0, w0.y, bgv.y)), 0.f);
        float v2 = fmaxf(fmaf(s1, w1.z, fmaf(s0, w0.z, bgv.z)), 0.f);
        float v3 = fmaxf(fmaf(s1, w1.w, fmaf(s0, w0.w, bgv.w)), 0.f);

        float sum = v0 + v1 + v2 + v3;
        float sq  = v0 * v0 + v1 * v1 + v2 * v2 + v3 * v3;
        #pragma unroll
        for (int o = 1; o < 64; o <<= 1) {
            sum += __shfl_xor(sum, o, 64);
            sq  += __shfl_xor(sq,  o, 64);
        }
        const float mu   = sum * (1.0f / HIDDEN);
        const float var  = sq * (1.0f / HIDDEN) - mu * mu;
        const float rstd = rsqrtf(var + LN_EPS);

        a0 += (v0 - mu) * rstd * gv.x + bv.x;
        a1 += (v1 - mu) * rstd * gv.y + bv.y;
        a2 += (v2 - mu) * rstd * gv.z + bv.z;
        a3 += (v3 - mu) * rstd * gv.w + bv.w;
    }

    red[wv][lane * 4 + 0] = a0;
    red[wv][lane * 4 + 1] = a1;
    red[wv][lane * 4 + 2] = a2;
    red[wv][lane * 4 + 3] = a3;
    __syncthreads();
    if (tid < HIDDEN) {
        float s = 0.f;
        #pragma unroll
        for (int w = 0; w < 16; ++w) s += red[w][tid];
        Ppart[(size_t)bid * HIDDEN + tid] = s;
    }
}

// ----------------------------- pooled partial reduce + MLP head ----
__global__ __launch_bounds__(256) void mlp_kernel(const float* __restrict__ Ppart,
                                                  const float* __restrict__ Wh,
                                                  const float* __restrict__ bh,
                                                  const float* __restrict__ Wo,
                                                  const float* __restrict__ bo,
                                                  float* __restrict__ out) {
    __shared__ float p[HIDDEN], z[HIDDEN], logits[OUT_DIM];
    const int j = threadIdx.x;

    float s0 = 0.f;
    for (int b = 0; b < 256; ++b) s0 += Ppart[(size_t)b * HIDDEN + j];
    p[j] = s0;
    __syncthreads();

    float s = bh[j];
    for (int k = 0; k < HIDDEN; ++k) s = fmaf(p[k], Wh[k * HIDDEN + j], s);
    z[j] = fmaxf(s, 0.0f);
    __syncthreads();

    if (j < OUT_DIM) {
        float t = bo[j];
        for (int k = 0; k < HIDDEN; ++k) t = fmaf(z[k], Wo[k * OUT_DIM + j], t);
        logits[j] = t;
    }
    __syncthreads();

    if (j == 0) {
        float m = logits[0];
        for (int k = 1; k < OUT_DIM; ++k) m = fmaxf(m, logits[k]);
        float sum = 0.0f;
        for (int k = 0; k < OUT_DIM; ++k) sum += expf(logits[k] - m);
        const float lse = m + logf(sum);
        for (int k = 0; k < OUT_DIM; ++k) out[k] = logits[k] - lse;
    }
}

// ---------------------------------------------------------------- launch ----
extern "C" void kernel_launch(void* const* d_in, const int* in_sizes, int n_in,
                              void* d_out, int out_size, void* d_ws, size_t ws_size,
                              hipStream_t stream) {
    const float* nf    = (const float*)d_in[0];   // [N, 2]
    const int*   ei    = (const int*)  d_in[1];   // [2, E] int32
    const float* Wg    = (const float*)d_in[2];
    const float* bg    = (const float*)d_in[3];
    const float* gamma = (const float*)d_in[4];
    const float* beta  = (const float*)d_in[5];
    const float* Wh    = (const float*)d_in[6];
    const float* bh    = (const float*)d_in[7];
    const float* Wo    = (const float*)d_in[8];
    const float* bo    = (const float*)d_in[9];
    float* out = (float*)d_out;

    const int* srcp = ei;
    const int* dstp = ei + N_EDGES;

    // workspace: degp [ES*N] u16 | Tpart [ES*2N] f32 | dinv [N] | y [2N]
    //            | Ppart [256*H]   (~16.5 MB)
    unsigned short* degp = (unsigned short*)d_ws;
    float* Tpart  = (float*)(degp + (size_t)ES * N_NODES);
    float* dinvp  = Tpart + (size_t)ES * 2 * N_NODES;
    float* yp     = dinvp + N_NODES;
    float* Ppart  = yp + 2 * N_NODES;

    dim3 pg(ES, NP);
    hist_kernel<<<pg, 1024, 0, stream>>>(dstp, degp);
    dinv_y_kernel<<<(N_NODES + 255) / 256, 256, 0, stream>>>(degp, (const float2*)nf, dinvp, (float2*)yp);
    scatterp_kernel<<<pg, 1024, 0, stream>>>(srcp, dstp, (const float2*)yp, Tpart);
    ln_pool_kernel<<<256, 1024, 0, stream>>>(Tpart, (const float2*)yp, dinvp, Wg, bg, gamma, beta, Ppart);
    mlp_kernel<<<1, 256, 0, stream>>>(Ppart, Wh, bh, Wo, bo, out);
}

// Round 7
// 67.041 us; speedup vs baseline: 7.9967x; 1.0223x over previous
//
#include <hip/hip_runtime.h>
#include <math.h>

#define N_NODES 50000
#define N_EDGES 800000
#define HIDDEN  256
#define OUT_DIM 10
#define LN_EPS  1e-5f

#define NP    8                    // node partitions
#define PART  (N_NODES / NP)       // 6250 nodes per partition
#define ES    32                   // edge slices
#define EPSE  (N_EDGES / ES)       // 25000 edges per slice
#define NPB   256                  // nodes per ln block
#define LNB   ((N_NODES + NPB - 1) / NPB)   // 196 blocks
#define NH2   (N_NODES / 2)        // 25000 node pairs

// --------------------------------------------------- privatized histogram ----
// Block (slice, part): LDS histogram of its node range over its edge slice.
// int4 dst loads; partials packed as u16 pairs (per-slice count <= 25000).
__global__ __launch_bounds__(1024) void hist_kernel(const int4* __restrict__ dst4,
                                                    unsigned* __restrict__ degp32) {
    __shared__ unsigned hist[PART];          // 25 KB
    const int tid = threadIdx.x;
    for (int i = tid; i < PART; i += 1024) hist[i] = 0u;
    __syncthreads();

    const int base = blockIdx.y * PART;
    const int b0 = blockIdx.x * (EPSE / 4);
    for (int i = tid; i < EPSE / 4; i += 1024) {
        const int4 d = dst4[b0 + i];
        unsigned r;
        r = (unsigned)(d.x - base); if (r < PART) atomicAdd(&hist[r], 1u);
        r = (unsigned)(d.y - base); if (r < PART) atomicAdd(&hist[r], 1u);
        r = (unsigned)(d.z - base); if (r < PART) atomicAdd(&hist[r], 1u);
        r = (unsigned)(d.w - base); if (r < PART) atomicAdd(&hist[r], 1u);
    }
    __syncthreads();

    unsigned* outp = degp32 + (size_t)blockIdx.x * NH2 + base / 2;
    for (int i = tid; i < PART / 2; i += 1024)
        outp[i] = (hist[2 * i] & 0xFFFFu) | (hist[2 * i + 1] << 16);
}

// deg partials -> dinv = rsqrt(deg+1), y = dinv * x   (2 nodes per thread)
__global__ __launch_bounds__(256) void dinv_y_kernel(const unsigned* __restrict__ degp32,
                                                     const float4* __restrict__ nf4,
                                                     float2* __restrict__ dinv2,
                                                     float4* __restrict__ y4) {
    const int t = blockIdx.x * 256 + threadIdx.x;   // pair index
    if (t >= NH2) return;
    unsigned s0 = 0, s1 = 0;
    #pragma unroll
    for (int s = 0; s < ES; ++s) {
        const unsigned d = degp32[(size_t)s * NH2 + t];
        s0 += d & 0xFFFFu;
        s1 += d >> 16;
    }
    const float di0 = rsqrtf((float)s0 + 1.0f);
    const float di1 = rsqrtf((float)s1 + 1.0f);
    dinv2[t] = make_float2(di0, di1);
    const float4 x = nf4[t];
    y4[t] = make_float4(di0 * x.x, di0 * x.y, di1 * x.z, di1 * x.w);
}

// ------------------------------------------------ privatized edge scatter ----
// Tpart[slice][d] = sum over slice's edges with dst=d of y[src]
// Also zeroes the ticket counter for the next kernel (block (0,0)).
__global__ __launch_bounds__(1024) void scatterp_kernel(const int* __restrict__ src,
                                                        const int4* __restrict__ dst4,
                                                        const float2* __restrict__ y,
                                                        float* __restrict__ Tpart,
                                                        unsigned* __restrict__ ticket) {
    __shared__ float T[2 * PART];            // 50 KB
    const int tid = threadIdx.x;
    if (blockIdx.x == 0 && blockIdx.y == 0 && tid == 0)
        __hip_atomic_store(ticket, 0u, __ATOMIC_RELAXED, __HIP_MEMORY_SCOPE_AGENT);
    for (int i = tid; i < 2 * PART; i += 1024) T[i] = 0.f;
    __syncthreads();

    const int base = blockIdx.y * PART;
    const int e0 = blockIdx.x * EPSE;
    const int b0 = blockIdx.x * (EPSE / 4);
    for (int i = tid; i < EPSE / 4; i += 1024) {
        const int4 d = dst4[b0 + i];
        const int e = e0 + 4 * i;
        unsigned r;
        r = (unsigned)(d.x - base);
        if (r < PART) { const float2 ys = y[src[e]];     atomicAdd(&T[2*r], ys.x); atomicAdd(&T[2*r+1], ys.y); }
        r = (unsigned)(d.y - base);
        if (r < PART) { const float2 ys = y[src[e + 1]]; atomicAdd(&T[2*r], ys.x); atomicAdd(&T[2*r+1], ys.y); }
        r = (unsigned)(d.z - base);
        if (r < PART) { const float2 ys = y[src[e + 2]]; atomicAdd(&T[2*r], ys.x); atomicAdd(&T[2*r+1], ys.y); }
        r = (unsigned)(d.w - base);
        if (r < PART) { const float2 ys = y[src[e + 3]]; atomicAdd(&T[2*r], ys.x); atomicAdd(&T[2*r+1], ys.y); }
    }
    __syncthreads();

    float* outp = Tpart + (size_t)blockIdx.x * (2 * N_NODES) + 2 * base;
    for (int i = tid; i < 2 * PART; i += 1024) outp[i] = T[i];
}

// -- Tpart reduce (block-local) + GCN expand + ReLU + LN + pool + MLP head ----
// Block b owns nodes [b*NPB, ...): reduces Tpart for its range into LDS,
// wave-per-node LN, plain-stores a pooled partial row, then the LAST block
// (ticket) reduces the partials and runs the MLP head. One acquire total.
__global__ __launch_bounds__(1024) void ln_pool_mlp_kernel(
    const float* __restrict__ Tpart,
    const float2* __restrict__ y,
    const float* __restrict__ dinv,
    const float* __restrict__ Wg, const float* __restrict__ bg,
    const float* __restrict__ gamma, const float* __restrict__ beta,
    const float* __restrict__ Wh, const float* __restrict__ bh,
    const float* __restrict__ Wo, const float* __restrict__ bo,
    float* __restrict__ Ppart,
    unsigned* __restrict__ ticket,
    float* __restrict__ out)
{
    const int tid = threadIdx.x;
    const int bid = blockIdx.x;
    const int n0  = bid * NPB;
    const int n1  = (n0 + NPB < N_NODES) ? n0 + NPB : N_NODES;
    const int len2 = 2 * (n1 - n0);

    __shared__ float Th[2][2 * NPB];         // 4 KB: two 16-slice halves
    __shared__ float red[16][HIDDEN];        // 16 KB, reused by MLP phase
    __shared__ int is_last;

    // block-local Tpart reduction, all 1024 threads (512 cols x 2 halves)
    {
        const int i = tid & 511;
        const int h = tid >> 9;
        if (i < len2) {
            float s = 0.f;
            #pragma unroll
            for (int p = 0; p < 16; ++p)
                s += Tpart[(size_t)(h * 16 + p) * (2 * N_NODES) + 2 * n0 + i];
            Th[h][i] = s;
        }
    }
    __syncthreads();

    const int lane = tid & 63;
    const int wv   = tid >> 6;

    const float4 w0  = *reinterpret_cast<const float4*>(&Wg[lane * 4]);
    const float4 w1  = *reinterpret_cast<const float4*>(&Wg[HIDDEN + lane * 4]);
    const float4 bgv = *reinterpret_cast<const float4*>(&bg[lane * 4]);
    const float4 gv  = *reinterpret_cast<const float4*>(&gamma[lane * 4]);
    const float4 bv  = *reinterpret_cast<const float4*>(&beta[lane * 4]);

    float a0 = 0.f, a1 = 0.f, a2 = 0.f, a3 = 0.f;

    for (int n = n0 + wv; n < n1; n += 16) {
        const float di = dinv[n];
        const float2 yn = y[n];
        const int idx = 2 * (n - n0);
        const float s0 = di * (Th[0][idx]     + Th[1][idx]     + yn.x);
        const float s1 = di * (Th[0][idx + 1] + Th[1][idx + 1] + yn.y);

        float v0 = fmaxf(fmaf(s1, w1.x, fmaf(s0, w0.x, bgv.x)), 0.f);
        float v1 = fmaxf(fmaf(s1, w1.y, fmaf(s0, w0.y, bgv.y)), 0.f);
        float v2 = fmaxf(fmaf(s1, w1.z, fmaf(s0, w0.z, bgv.z)), 0.f);
        float v3 = fmaxf(fmaf(s1, w1.w, fmaf(s0, w0.w, bgv.w)), 0.f);

        float sum = v0 + v1 + v2 + v3;
        float sq  = v0 * v0 + v1 * v1 + v2 * v2 + v3 * v3;
        #pragma unroll
        for (int o = 1; o < 64; o <<= 1) {
            sum += __shfl_xor(sum, o, 64);
            sq  += __shfl_xor(sq,  o, 64);
        }
        const float mu   = sum * (1.0f / HIDDEN);
        const float var  = sq * (1.0f / HIDDEN) - mu * mu;
        const float rstd = rsqrtf(var + LN_EPS);

        a0 += (v0 - mu) * rstd * gv.x + bv.x;
        a1 += (v1 - mu) * rstd * gv.y + bv.y;
        a2 += (v2 - mu) * rstd * gv.z + bv.z;
        a3 += (v3 - mu) * rstd * gv.w + bv.w;
    }

    red[wv][lane * 4 + 0] = a0;
    red[wv][lane * 4 + 1] = a1;
    red[wv][lane * 4 + 2] = a2;
    red[wv][lane * 4 + 3] = a3;
    __syncthreads();
    if (tid < HIDDEN) {
        float s = 0.f;
        #pragma unroll
        for (int w = 0; w < 16; ++w) s += red[w][tid];
        Ppart[(size_t)bid * HIDDEN + tid] = s;
    }
    __syncthreads();

    // ------------- ticket: last block runs the MLP head -------------------
    if (tid == 0) {
        const unsigned old = __hip_atomic_fetch_add(ticket, 1u, __ATOMIC_ACQ_REL,
                                                    __HIP_MEMORY_SCOPE_AGENT);
        is_last = (old == (unsigned)(gridDim.x - 1));
    }
    __syncthreads();
    if (!is_last) return;

    const int g = tid >> 8;      // 0..3
    const int j = tid & 255;

    // pooled = sum of LNB partial rows (deterministic order per thread)
    {
        float s = 0.f;
        for (int b = g; b < LNB; b += 4) s += Ppart[(size_t)b * HIDDEN + j];
        red[g][j] = s;
    }
    __syncthreads();
    if (tid < HIDDEN)
        red[4][tid] = red[0][tid] + red[1][tid] + red[2][tid] + red[3][tid];
    __syncthreads();

    // z = relu(bh + pooled @ Wh)
    {
        float acc = 0.f;
        for (int k = g * 64; k < g * 64 + 64; ++k)
            acc = fmaf(red[4][k], Wh[k * HIDDEN + j], acc);
        red[8 + g][j] = acc;
    }
    __syncthreads();
    if (tid < HIDDEN)
        red[5][tid] = fmaxf(bh[tid] + red[8][tid] + red[9][tid] + red[10][tid] + red[11][tid], 0.f);
    __syncthreads();

    // logits = z @ Wo + bo  (one wave per output)
    if (wv < OUT_DIM) {
        float acc = 0.f;
        #pragma unroll
        for (int q = 0; q < 4; ++q) {
            const int k = lane + 64 * q;
            acc = fmaf(red[5][k], Wo[k * OUT_DIM + wv], acc);
        }
        #pragma unroll
        for (int o = 1; o < 64; o <<= 1) acc += __shfl_xor(acc, o, 64);
        if (lane == 0) red[6][wv] = acc + bo[wv];
    }
    __syncthreads();

    if (tid == 0) {
        float m = red[6][0];
        for (int k = 1; k < OUT_DIM; ++k) m = fmaxf(m, red[6][k]);
        float sum = 0.f;
        for (int k = 0; k < OUT_DIM; ++k) sum += expf(red[6][k] - m);
        const float lse = m + logf(sum);
        for (int k = 0; k < OUT_DIM; ++k) out[k] = red[6][k] - lse;
    }
}

// ---------------------------------------------------------------- launch ----
extern "C" void kernel_launch(void* const* d_in, const int* in_sizes, int n_in,
                              void* d_out, int out_size, void* d_ws, size_t ws_size,
                              hipStream_t stream) {
    const float* nf    = (const float*)d_in[0];   // [N, 2]
    const int*   ei    = (const int*)  d_in[1];   // [2, E] int32
    const float* Wg    = (const float*)d_in[2];
    const float* bg    = (const float*)d_in[3];
    const float* gamma = (const float*)d_in[4];
    const float* beta  = (const float*)d_in[5];
    const float* Wh    = (const float*)d_in[6];
    const float* bh    = (const float*)d_in[7];
    const float* Wo    = (const float*)d_in[8];
    const float* bo    = (const float*)d_in[9];
    float* out = (float*)d_out;

    const int* srcp = ei;
    const int* dstp = ei + N_EDGES;               // 3.2MB offset: 16B-aligned

    // workspace: ticket u32[16] pad to 64B | degp32 [ES*N/2] u32 (3.2MB)
    //            | Tpart [ES*2N] f32 (12.8MB) | dinv [N] | y [2N] | Ppart [LNB*H]
    unsigned* ticket = (unsigned*)d_ws;
    unsigned* degp32 = ticket + 16;
    float* Tpart  = (float*)(degp32 + (size_t)ES * NH2);
    float* dinvp  = Tpart + (size_t)ES * 2 * N_NODES;
    float* yp     = dinvp + N_NODES;
    float* Ppart  = yp + 2 * N_NODES;

    dim3 pg(ES, NP);
    hist_kernel<<<pg, 1024, 0, stream>>>((const int4*)dstp, degp32);
    dinv_y_kernel<<<(NH2 + 255) / 256, 256, 0, stream>>>(degp32, (const float4*)nf,
                                                         (float2*)dinvp, (float4*)yp);
    scatterp_kernel<<<pg, 1024, 0, stream>>>(srcp, (const int4*)dstp, (const float2*)yp,
                                             Tpart, ticket);
    ln_pool_mlp_kernel<<<LNB, 1024, 0, stream>>>(Tpart, (const float2*)yp, dinvp,
                                                 Wg, bg, gamma, beta, Wh, bh, Wo, bo,
                                                 Ppart, ticket, out);
}